// Round 6
// baseline (658.447 us; speedup 1.0000x reference)
//
#include <hip/hip_runtime.h>
#include <hip/hip_cooperative_groups.h>
#include <math.h>

namespace cg = cooperative_groups;

#define SE_B   32
#define SE_C   256
#define SE_R   16
#define SE_HW  16384            // 128*128 floats per plane
#define NBLK   512              // 2 blocks/CU co-resident (safe)
#define PPB    2                // planes per block per iteration
#define NITER  8                // 512*2*8 = 8192 planes

typedef float v4f __attribute__((ext_vector_type(4)));

// ================= fused cooperative kernel =================
// Each block holds 2 planes (32 float4/thread = 128 VGPRs) in registers
// across a grid sync, so x is read from HBM exactly once.
__global__ __launch_bounds__(256, 2) void se_fused_kernel(
    const float* __restrict__ x,
    const float* __restrict__ w1,     // [R, C]
    const float* __restrict__ w2,     // [C, R]
    float* __restrict__ out,
    float* __restrict__ pooled) {     // ws: [8192]
    cg::grid_group grid = cg::this_grid();
    const int t = threadIdx.x;

    __shared__ float wsum[2][4];
    __shared__ float p_lds[SE_C];
    __shared__ float hpart[SE_R][SE_R + 1];
    __shared__ float h_lds[SE_R];
    __shared__ float g_lds[PPB];

    for (int g = 0; g < NITER; ++g) {
        const int p0 = g * (NBLK * PPB) + blockIdx.x * PPB;   // first plane
        const int b  = p0 >> 8;            // batch (same for both planes)
        const int c0 = p0 & 255;
        const v4f* xv = reinterpret_cast<const v4f*>(x)  + (size_t)p0 * (SE_HW / 4);
        v4f*       ov = reinterpret_cast<v4f*>(out)      + (size_t)p0 * (SE_HW / 4);

        // ---- pool: both planes into registers, per-plane sums ----
        v4f d0[16], d1[16];
#pragma unroll
        for (int k = 0; k < 16; ++k) d0[k] = xv[k * 256 + t];
#pragma unroll
        for (int k = 0; k < 16; ++k) d1[k] = xv[4096 + k * 256 + t];
        float s0 = 0.f, s1 = 0.f;
#pragma unroll
        for (int k = 0; k < 16; ++k) {
            s0 += (d0[k].x + d0[k].y) + (d0[k].z + d0[k].w);
            s1 += (d1[k].x + d1[k].y) + (d1[k].z + d1[k].w);
        }
#pragma unroll
        for (int off = 32; off > 0; off >>= 1) {
            s0 += __shfl_down(s0, off, 64);
            s1 += __shfl_down(s1, off, 64);
        }
        if ((t & 63) == 0) { wsum[0][t >> 6] = s0; wsum[1][t >> 6] = s1; }
        __syncthreads();
        if (t < 2) {
            const float tot = (wsum[t][0] + wsum[t][1]) + (wsum[t][2] + wsum[t][3]);
            __hip_atomic_store(&pooled[p0 + t], tot * (1.0f / SE_HW),
                               __ATOMIC_RELAXED, __HIP_MEMORY_SCOPE_AGENT);
        }

        grid.sync();                       // pooled[] for batches 4g..4g+3 ready

        // ---- gate for this block's batch ----
        p_lds[t] = __hip_atomic_load(&pooled[b * SE_C + t],
                                     __ATOMIC_RELAXED, __HIP_MEMORY_SCOPE_AGENT);
        __syncthreads();
        {   // h[r] = relu(sum_c p[c]*w1[r,c]); split C into 16 segments
            const int r = t & 15, seg = t >> 4;
            float acc = 0.f;
#pragma unroll
            for (int j = 0; j < 16; ++j) {
                const int cc = seg * 16 + j;
                acc = fmaf(p_lds[cc], w1[r * SE_C + cc], acc);
            }
            hpart[r][seg] = acc;
        }
        __syncthreads();
        if (t < SE_R) {
            float acc = 0.f;
#pragma unroll
            for (int j = 0; j < 16; ++j) acc += hpart[t][j];
            h_lds[t] = fmaxf(acc, 0.f);
        }
        __syncthreads();
        if (t < PPB) {                     // one thread per plane's gate
            float acc = 0.f;
#pragma unroll
            for (int r = 0; r < SE_R; ++r)
                acc = fmaf(h_lds[r], w2[(c0 + t) * SE_R + r], acc);
            g_lds[t] = 1.0f / (1.0f + expf(-acc));
        }
        __syncthreads();
        const float g0 = g_lds[0], g1 = g_lds[1];

        // ---- scale registers, NT store ----
#pragma unroll
        for (int k = 0; k < 16; ++k) {
            v4f v0 = d0[k] * g0;
            __builtin_nontemporal_store(v0, &ov[k * 256 + t]);
        }
#pragma unroll
        for (int k = 0; k < 16; ++k) {
            v4f v1 = d1[k] * g1;
            __builtin_nontemporal_store(v1, &ov[4096 + k * 256 + t]);
        }
        __syncthreads();                   // protect LDS before next iter
    }
}

// ================= fallback path (proven 272 us) =================
__global__ __launch_bounds__(256) void se_pool_kernel(const float* __restrict__ x,
                                                      float* __restrict__ pooled) {
    const int bc = blockIdx.x;
    const v4f* xv = reinterpret_cast<const v4f*>(x + (size_t)bc * SE_HW);
    const int t = threadIdx.x;
    float s = 0.f;
#pragma unroll
    for (int k = 0; k < 16; ++k) {
        v4f v = xv[t + k * 256];
        s += (v.x + v.y) + (v.z + v.w);
    }
#pragma unroll
    for (int off = 32; off > 0; off >>= 1) s += __shfl_down(s, off, 64);
    __shared__ float ws[4];
    if ((t & 63) == 0) ws[t >> 6] = s;
    __syncthreads();
    if (t == 0) pooled[bc] = ((ws[0] + ws[1]) + (ws[2] + ws[3])) * (1.0f / SE_HW);
}

__global__ __launch_bounds__(256) void se_gate_kernel(const float* __restrict__ pooled,
                                                      const float* __restrict__ w1,
                                                      const float* __restrict__ w2,
                                                      float* __restrict__ gate) {
    const int b = blockIdx.x;
    const int t = threadIdx.x;
    __shared__ float p[SE_C];
    __shared__ float h[SE_R];
    p[t] = pooled[b * SE_C + t];
    __syncthreads();
    if (t < SE_R) {
        float acc = 0.f;
        for (int c = 0; c < SE_C; ++c) acc = fmaf(p[c], w1[t * SE_C + c], acc);
        h[t] = fmaxf(acc, 0.f);
    }
    __syncthreads();
    float acc = 0.f;
#pragma unroll
    for (int r = 0; r < SE_R; ++r) acc = fmaf(h[r], w2[t * SE_R + r], acc);
    gate[b * SE_C + t] = 1.0f / (1.0f + expf(-acc));
}

__global__ __launch_bounds__(256) void se_scale_kernel(const float* __restrict__ x,
                                                       const float* __restrict__ gate,
                                                       float* __restrict__ out) {
    const int plane = (SE_B * SE_C) - 1 - blockIdx.x;
    const float g = gate[plane];
    const v4f* xv = reinterpret_cast<const v4f*>(x) + (size_t)plane * (SE_HW / 4);
    v4f* ov = reinterpret_cast<v4f*>(out) + (size_t)plane * (SE_HW / 4);
    const int t = threadIdx.x;
#pragma unroll
    for (int k = 15; k >= 0; --k) {
        const int i = k * 256 + t;
        v4f v = xv[i];
        v *= g;
        __builtin_nontemporal_store(v, &ov[i]);
    }
}

extern "C" void kernel_launch(void* const* d_in, const int* in_sizes, int n_in,
                              void* d_out, int out_size, void* d_ws, size_t ws_size,
                              hipStream_t stream) {
    const float* x  = (const float*)d_in[0];   // [32,256,128,128]
    const float* w1 = (const float*)d_in[1];   // [16,256]
    const float* w2 = (const float*)d_in[2];   // [256,16]
    float* out = (float*)d_out;
    float* pooled = (float*)d_ws;              // 8192 floats
    float* gatebuf = (float*)((char*)d_ws + SE_B * SE_C * sizeof(float));

    void* args[] = { (void*)&x, (void*)&w1, (void*)&w2, (void*)&out, (void*)&pooled };
    hipError_t err = hipLaunchCooperativeKernel((void*)se_fused_kernel,
                                                dim3(NBLK), dim3(256),
                                                args, 0, stream);
    if (err != hipSuccess) {
        (void)hipGetLastError();               // clear sticky error
        se_pool_kernel<<<SE_B * SE_C, 256, 0, stream>>>(x, pooled);
        se_gate_kernel<<<SE_B, 256, 0, stream>>>(pooled, w1, w2, gatebuf);
        se_scale_kernel<<<SE_B * SE_C, 256, 0, stream>>>(x, gatebuf, out);
    }
}

// Round 7
// 252.025 us; speedup vs baseline: 2.6126x; 2.6126x over previous
//
#include <hip/hip_runtime.h>
#include <math.h>

#define SE_B   32
#define SE_C   256
#define SE_R   16
#define SE_HW  16384                 // floats per plane
#define SE_NP  (SE_B * SE_C)         // 8192 planes

typedef float v4f __attribute__((ext_vector_type(4)));
typedef unsigned int u32;
typedef u32 v4u __attribute__((ext_vector_type(4)));

// pack two fp32 -> one u32 of two bf16 (round-half-up)
__device__ inline u32 pk(float a, float b) {
    u32 ua = __float_as_uint(a), ub = __float_as_uint(b);
    return ((ua + 0x8000u) >> 16) | ((ub + 0x8000u) & 0xffff0000u);
}

// ---- K1: pool + bf16-pack. One block per plane, ascending. ----
// x is read with NT loads (hint: don't retain); xh written normally so it
// is the only L3-allocating stream (268 MB ~ fits the 256 MiB L3).
__global__ __launch_bounds__(256) void se_pool_pack(const float* __restrict__ x,
                                                    u32* __restrict__ xh,
                                                    float* __restrict__ pooled) {
    const int plane = blockIdx.x;
    const int t = threadIdx.x;
    const v4f* xv = reinterpret_cast<const v4f*>(x) + (size_t)plane * (SE_HW / 4);
    v4u* xh4 = reinterpret_cast<v4u*>(xh) + (size_t)plane * (SE_HW / 8);
    float s = 0.f;
#pragma unroll
    for (int j = 0; j < 8; ++j) {
        v4f a = __builtin_nontemporal_load(&xv[(2 * j) * 256 + t]);
        v4f b = __builtin_nontemporal_load(&xv[(2 * j + 1) * 256 + t]);
        s += (a.x + a.y) + (a.z + a.w) + (b.x + b.y) + (b.z + b.w);
        v4u p;
        p.x = pk(a.x, a.y); p.y = pk(a.z, a.w);
        p.z = pk(b.x, b.y); p.w = pk(b.z, b.w);
        xh4[j * 256 + t] = p;                       // normal store -> L3 resident
    }
#pragma unroll
    for (int off = 32; off > 0; off >>= 1) s += __shfl_down(s, off, 64);
    __shared__ float ws[4];
    if ((t & 63) == 0) ws[t >> 6] = s;
    __syncthreads();
    if (t == 0) pooled[plane] = ((ws[0] + ws[1]) + (ws[2] + ws[3])) * (1.0f / SE_HW);
}

// ---- K2: tiny MLP gate (fp32 pooled -> gate). ----
__global__ __launch_bounds__(256) void se_gate_kernel(const float* __restrict__ pooled,
                                                      const float* __restrict__ w1,
                                                      const float* __restrict__ w2,
                                                      float* __restrict__ gate) {
    const int b = blockIdx.x;
    const int t = threadIdx.x;
    __shared__ float p[SE_C];
    __shared__ float h[SE_R];
    p[t] = pooled[b * SE_C + t];
    __syncthreads();
    if (t < SE_R) {
        float acc = 0.f;
        for (int c = 0; c < SE_C; ++c) acc = fmaf(p[c], w1[t * SE_C + c], acc);
        h[t] = fmaxf(acc, 0.f);
    }
    __syncthreads();
    float acc = 0.f;
#pragma unroll
    for (int r = 0; r < SE_R; ++r) acc = fmaf(h[r], w2[t * SE_R + r], acc);
    gate[b * SE_C + t] = 1.0f / (1.0f + expf(-acc));
}

// ---- K3: scale from the bf16 copy. One block per plane, DESCENDING
// (xh tail is what K1 most recently wrote -> L3-hot). NT store out. ----
__global__ __launch_bounds__(256) void se_scale_bf16(const u32* __restrict__ xh,
                                                     const float* __restrict__ gate,
                                                     float* __restrict__ out) {
    const int plane = SE_NP - 1 - blockIdx.x;
    const int t = threadIdx.x;
    const float g = gate[plane];
    const v4u* xh4 = reinterpret_cast<const v4u*>(xh) + (size_t)plane * (SE_HW / 8);
    v4f* ov = reinterpret_cast<v4f*>(out) + (size_t)plane * (SE_HW / 4);
#pragma unroll
    for (int j = 0; j < 8; ++j) {
        v4u p = xh4[j * 256 + t];                   // normal load -> L3 hit hoped
        v4f a, b;
        a.x = __uint_as_float(p.x << 16);  a.y = __uint_as_float(p.x & 0xffff0000u);
        a.z = __uint_as_float(p.y << 16);  a.w = __uint_as_float(p.y & 0xffff0000u);
        b.x = __uint_as_float(p.z << 16);  b.y = __uint_as_float(p.z & 0xffff0000u);
        b.z = __uint_as_float(p.w << 16);  b.w = __uint_as_float(p.w & 0xffff0000u);
        a *= g; b *= g;
        __builtin_nontemporal_store(a, &ov[(2 * j) * 256 + t]);
        __builtin_nontemporal_store(b, &ov[(2 * j + 1) * 256 + t]);
    }
}

// ================= fallback (proven 272 us) if ws is too small =================
__global__ __launch_bounds__(256) void se_pool_kernel(const float* __restrict__ x,
                                                      float* __restrict__ pooled) {
    const int bc = blockIdx.x;
    const v4f* xv = reinterpret_cast<const v4f*>(x + (size_t)bc * SE_HW);
    const int t = threadIdx.x;
    float s = 0.f;
#pragma unroll
    for (int k = 0; k < 16; ++k) {
        v4f v = xv[t + k * 256];
        s += (v.x + v.y) + (v.z + v.w);
    }
#pragma unroll
    for (int off = 32; off > 0; off >>= 1) s += __shfl_down(s, off, 64);
    __shared__ float ws[4];
    if ((t & 63) == 0) ws[t >> 6] = s;
    __syncthreads();
    if (t == 0) pooled[bc] = ((ws[0] + ws[1]) + (ws[2] + ws[3])) * (1.0f / SE_HW);
}

__global__ __launch_bounds__(256) void se_scale_kernel(const float* __restrict__ x,
                                                       const float* __restrict__ gate,
                                                       float* __restrict__ out) {
    const int plane = SE_NP - 1 - blockIdx.x;
    const float g = gate[plane];
    const v4f* xv = reinterpret_cast<const v4f*>(x) + (size_t)plane * (SE_HW / 4);
    v4f* ov = reinterpret_cast<v4f*>(out) + (size_t)plane * (SE_HW / 4);
    const int t = threadIdx.x;
#pragma unroll
    for (int k = 15; k >= 0; --k) {
        const int i = k * 256 + t;
        v4f v = xv[i];
        v *= g;
        __builtin_nontemporal_store(v, &ov[i]);
    }
}

extern "C" void kernel_launch(void* const* d_in, const int* in_sizes, int n_in,
                              void* d_out, int out_size, void* d_ws, size_t ws_size,
                              hipStream_t stream) {
    const float* x  = (const float*)d_in[0];   // [32,256,128,128]
    const float* w1 = (const float*)d_in[1];   // [16,256]
    const float* w2 = (const float*)d_in[2];   // [256,16]
    float* out = (float*)d_out;

    float* pooled  = (float*)d_ws;                                   // 32 KiB
    float* gatebuf = (float*)((char*)d_ws + SE_NP * sizeof(float));  // 32 KiB
    u32*   xh      = (u32*)((char*)d_ws + 2 * SE_NP * sizeof(float));
    const size_t need = 2 * SE_NP * sizeof(float)
                      + (size_t)SE_NP * SE_HW * 2 /*bf16 bytes*/;

    if (ws_size >= need) {
        se_pool_pack<<<SE_NP, 256, 0, stream>>>(x, xh, pooled);
        se_gate_kernel<<<SE_B, 256, 0, stream>>>(pooled, w1, w2, gatebuf);
        se_scale_bf16<<<SE_NP, 256, 0, stream>>>(xh, gatebuf, out);
    } else {
        se_pool_kernel<<<SE_NP, 256, 0, stream>>>(x, pooled);
        se_gate_kernel<<<SE_B, 256, 0, stream>>>(pooled, w1, w2, gatebuf);
        se_scale_kernel<<<SE_NP, 256, 0, stream>>>(x, gatebuf, out);
    }
}